// Round 19
// baseline (171.911 us; speedup 1.0000x reference)
//
#include <hip/hip_runtime.h>
#include <hip/hip_bf16.h>

// B=4, N0=2048 (N=1024 diff + 1024 cond), C=768, H=12, hd=64. All fp32 I/O.
// SINGLE f16 everywhere (R13-R15); fixed-max softmax (R16).
// R19 = R16's proven 2-phase 32KB GEMM loop (best occupancy) + R17's C^T
// q/k epilogue (ushort4 stores) via a block-uniform runtime branch, single
// qkv launch (R18's split kernels regressed; R17's 3-buf pipeline regressed).
//   0. prep: wT f16 (1 launch); x f16 -> d_out scratch
//   1. qkv [f16 MFMA] -> q f16 /8, k f16 (C^T epi), vt f16 (B,H,64,N)
//   2. osp = attn(q_d,k_d,vt_d)  [f16 MFMA] -> osp f16 (B*N,768)
//   3. vt2 = (osp @ w_proj_diff + b)^T  [f16 MFMA] -> f16 (B,H,64,N)
//   4+5 fused: P = exp(q_c k_c^T) once;
//        out[:, :N] = P @ vt2 / l (fp32), osp = P @ vt_c / l (f16)
//   6. out[:, N:] = osp @ w_proj_cond + b   [f16 MFMA]
// Lessons held: MFMA operands from LDS (R9); many small attn blocks (R10);
// no setprio/defer-max in lockstep attn (R11); occupancy > pipeline depth
// at 128^2 tile (R6/R17); single launch > split kernels (R18).

#define C_DIM 768
#define HEADS 12
#define HD 64
#define NSEQ 1024
#define BATCH 4
#define SZC 3145728  // BATCH*HEADS*NSEQ*HD

typedef short bf16x8 __attribute__((ext_vector_type(8)));       // raw 16-bit x8
typedef _Float16 f16x8 __attribute__((ext_vector_type(8)));
typedef float f32x4 __attribute__((ext_vector_type(4)));
typedef unsigned int u32x4v __attribute__((ext_vector_type(4)));

typedef __attribute__((address_space(3))) unsigned int lds_u32_t;
typedef __attribute__((address_space(1))) const unsigned int glb_u32_t;

__device__ __forceinline__ void gl16(const void* g, void* l) {
  __builtin_amdgcn_global_load_lds((glb_u32_t*)g, (lds_u32_t*)l, 16, 0, 0);
}

__device__ __forceinline__ unsigned short f2h(float x) {
  _Float16 h = (_Float16)x;
  return *reinterpret_cast<unsigned short*>(&h);
}

// ---------------------------------------------------------------------------
// Merged weight prep: 4 weights -> wT f16 single, z selects.
// ---------------------------------------------------------------------------
__global__ __launch_bounds__(256) void split_wT4_k(
    const float* __restrict__ w0, const float* __restrict__ w1,
    const float* __restrict__ w2, const float* __restrict__ w3,
    unsigned short* __restrict__ t0, unsigned short* __restrict__ t1,
    unsigned short* __restrict__ t2, unsigned short* __restrict__ t3)
{
  const int z = blockIdx.z;
  const int N = (z < 2) ? 2304 : 768;
  if (blockIdx.x * 32 >= N) return;
  const float* w = (z == 0) ? w0 : (z == 1) ? w1 : (z == 2) ? w2 : w3;
  unsigned short* th = (z == 0) ? t0 : (z == 1) ? t1 : (z == 2) ? t2 : t3;

  __shared__ float T[32][33];
  const int n0 = blockIdx.x * 32, k0 = blockIdx.y * 32;
  const int tx = threadIdx.x, ty = threadIdx.y;
#pragma unroll
  for (int i = 0; i < 4; ++i) {
    int k = ty + i * 8;
    T[k][tx] = w[(size_t)(k0 + k) * N + n0 + tx];
  }
  __syncthreads();
#pragma unroll
  for (int i = 0; i < 4; ++i) {
    int n = ty + i * 8;
    th[(size_t)(n0 + n) * 768 + k0 + tx] = f2h(T[tx][n]);
  }
}

// ---------------------------------------------------------------------------
// x prep: elementwise f16 convert of x -> xs.
// ---------------------------------------------------------------------------
__global__ __launch_bounds__(256) void split_x_k(
    const float* __restrict__ x, unsigned short* __restrict__ xs)
{
  const size_t i = ((size_t)blockIdx.x * 256 + threadIdx.x) * 8;
  float4 f0 = *(const float4*)(x + i);
  float4 f1 = *(const float4*)(x + i + 4);
  float fa[8] = {f0.x, f0.y, f0.z, f0.w, f1.x, f1.y, f1.z, f1.w};
  unsigned short hv[8];
#pragma unroll
  for (int j = 0; j < 8; ++j) hv[j] = f2h(fa[j]);
  *(bf16x8*)(xs + i) = *(bf16x8*)hv;
}

// ---------------------------------------------------------------------------
// Unified single-f16 GEMM, 2-phase dbuf (R16 loop), all-gl16 (pre-swizzled
// sources, chunk^((row>>1)&3)). 128x128 tile, BK=32, 4 waves, LDS 32 KB.
// EPI 0: qkv; bx<12 -> swapped MFMA (C^T) + ushort4 q/k stores; bx>=12 -> vt.
// EPI 1: proj -> fp32 d_out[:, N:]. EPI 2: proj -> vt2 f16 T.
// ---------------------------------------------------------------------------
template <int EPI>
__global__ __launch_bounds__(256) void gemm2_k(
    const unsigned short* __restrict__ A,
    const unsigned short* __restrict__ B0, const unsigned short* __restrict__ B1,
    const float* __restrict__ bias,
    unsigned short* __restrict__ ws_split,
    float* __restrict__ outf,
    unsigned short* __restrict__ vt_out)
{
  __shared__ __attribute__((aligned(16))) unsigned short lds[16384];  // 32 KB

  const int tid = threadIdx.x;
  const int lane = tid & 63;
  const int wave = tid >> 6;
  const int wr = wave >> 1, wc = wave & 1;
  const int arow = lane & 15, agrp = lane >> 4;

  int bx, by, half;
  if constexpr (EPI == 0) {
    int orig = blockIdx.x + 18 * blockIdx.y + 576 * blockIdx.z;  // [0,1152)
    int xcd = orig & 7, l = orig >> 3;
    int g = xcd * 6 + (l / 24);
    int r = l % 24;
    int rest = g / 6;
    bx = (g % 6) * 3 + (r % 3);
    by = (rest & 3) * 8 + (r / 3);
    half = rest >> 2;
  } else {
    int flat = blockIdx.x + 6 * blockIdx.y;  // nwg = 192
    flat = (flat & 7) * 24 + (flat >> 3);
    bx = flat % 6;
    by = flat / 6;
    half = 0;
  }

  const int m0 = by * 128;
  const int b = m0 >> 10, nloc = m0 & 1023;
  const int c0 = bx * 128;
  const unsigned short* __restrict__ Bp = (EPI == 0 && half) ? B1 : B0;
  const size_t Arow = (EPI == 0) ? (size_t)(b * 2048 + half * 1024 + nloc)
                                 : (size_t)m0;
  const bool qk_mode = (EPI == 0) && (bx < 12);   // block-uniform

  const int gr = tid >> 2, gc = (tid & 3) ^ ((tid >> 3) & 3);
  const unsigned short* gA = A + (Arow + gr) * 768 + gc * 8;
  const unsigned short* gB = Bp + (size_t)(c0 + gr) * 768 + gc * 8;
  const int wo = wave * 512;

  f32x4 acc[4][4];
#pragma unroll
  for (int i = 0; i < 4; ++i)
#pragma unroll
    for (int j = 0; j < 4; ++j) acc[i][j] = f32x4{0.f, 0.f, 0.f, 0.f};

  auto stage4 = [&](int k0, int bo) {
    gl16(gA + k0, lds + bo + wo);
    gl16(gA + k0 + 64 * 768, lds + bo + wo + 2048);
    gl16(gB + k0, lds + bo + 4096 + wo);
    gl16(gB + k0 + 64 * 768, lds + bo + 4096 + wo + 2048);
  };

  stage4(0, 0);
  asm volatile("s_waitcnt vmcnt(0)" ::: "memory");
  __builtin_amdgcn_s_barrier();

  int cur = 0;
  for (int t = 0; t < 24; ++t) {
    const int bo = cur * 8192;
    if (t < 23) stage4((t + 1) * 32, bo ^ 8192);

    f16x8 af[4], bf[4];
#pragma unroll
    for (int mf = 0; mf < 4; ++mf) {
      const int row = wr * 64 + mf * 16 + arow;
      const int off = bo + row * 32 + ((agrp ^ ((row >> 1) & 3)) << 3);
      af[mf] = *(const f16x8*)(lds + off);
    }
#pragma unroll
    for (int nf = 0; nf < 4; ++nf) {
      const int row = wc * 64 + nf * 16 + arow;
      const int off = bo + row * 32 + ((agrp ^ ((row >> 1) & 3)) << 3);
      bf[nf] = *(const f16x8*)(lds + 4096 + off);
    }
    if (qk_mode) {
      // swapped operands: acc = C^T fragmentwise
#pragma unroll
      for (int mf = 0; mf < 4; ++mf)
#pragma unroll
        for (int nf = 0; nf < 4; ++nf)
          acc[mf][nf] = __builtin_amdgcn_mfma_f32_16x16x32_f16(bf[nf], af[mf], acc[mf][nf], 0, 0, 0);
    } else {
#pragma unroll
      for (int mf = 0; mf < 4; ++mf)
#pragma unroll
        for (int nf = 0; nf < 4; ++nf)
          acc[mf][nf] = __builtin_amdgcn_mfma_f32_16x16x32_f16(af[mf], bf[nf], acc[mf][nf], 0, 0, 0);
    }

    if (t < 23) {
      asm volatile("s_waitcnt vmcnt(0)" ::: "memory");
      __builtin_amdgcn_s_barrier();
      cur ^= 1;
    }
  }

  if constexpr (EPI == 0) {
    const int t_ = c0 / 768;                 // 0=q, 1=k, 2=v
    const int rem0 = c0 - t_ * 768;
    unsigned short* base = ws_split + (size_t)(half * 3) * SZC;
    if (t_ < 2) {
      // C^T epilogue: d on (wc,nf,agrp,ri), n on (wr,mf,arow) -> ushort4
      unsigned short* arr = base + (size_t)t_ * SZC;
      const float qs = (t_ == 0) ? 0.125f : 1.0f;
#pragma unroll
      for (int nf = 0; nf < 4; ++nf) {
        const int rem_c = rem0 + wc * 64 + nf * 16 + agrp * 4;
        const int h = rem_c >> 6;
        const int d = rem_c & 63;
        const size_t bh_ = (size_t)(b * HEADS + h);
#pragma unroll
        for (int mf = 0; mf < 4; ++mf) {
          const int n = nloc + wr * 64 + mf * 16 + arow;
          unsigned short hv[4];
#pragma unroll
          for (int ri = 0; ri < 4; ++ri) hv[ri] = f2h(acc[mf][nf][ri] * qs);
          *(ushort4*)(arr + (bh_ * NSEQ + n) * HD + d) = *(ushort4*)hv;
        }
      }
    } else {
      // vt transposed (B,H,64,N): n contiguous over ri
      unsigned short* vt_a = base + 2 * (size_t)SZC;
#pragma unroll
      for (int nf = 0; nf < 4; ++nf) {
        const int rc = rem0 + wc * 64 + nf * 16 + arow;
        const int h = rc >> 6;
        const int d = rc & 63;
        const size_t bh_ = (size_t)(b * HEADS + h);
#pragma unroll
        for (int mf = 0; mf < 4; ++mf) {
          const int n = nloc + wr * 64 + mf * 16 + agrp * 4;
          unsigned short hv[4];
#pragma unroll
          for (int ri = 0; ri < 4; ++ri) hv[ri] = f2h(acc[mf][nf][ri]);
          *(ushort4*)(vt_a + (bh_ * HD + d) * NSEQ + n) = *(ushort4*)hv;
        }
      }
    }
  } else if constexpr (EPI == 1) {
#pragma unroll
    for (int nf = 0; nf < 4; ++nf) {
      const int cg = c0 + wc * 64 + nf * 16 + arow;
      const float bv = bias[cg];
#pragma unroll
      for (int mf = 0; mf < 4; ++mf) {
#pragma unroll
        for (int ri = 0; ri < 4; ++ri) {
          const int m = m0 + wr * 64 + mf * 16 + agrp * 4 + ri;
          const int bb = m >> 10, n = m & 1023;
          outf[(size_t)bb * (2048 * 768) + (size_t)(1024 + n) * 768 + cg] =
              acc[mf][nf][ri] + bv;
        }
      }
    }
  } else {  // EPI == 2: f16 transposed (B,H,64,N)
#pragma unroll
    for (int nf = 0; nf < 4; ++nf) {
      const int cg = c0 + wc * 64 + nf * 16 + arow;
      const int h = cg >> 6, d = cg & 63;
      const float bv = bias[cg];
#pragma unroll
      for (int mf = 0; mf < 4; ++mf) {
        const int m = m0 + wr * 64 + mf * 16 + agrp * 4;
        const int bb = m >> 10, n = m & 1023;
        unsigned short hv[4];
#pragma unroll
        for (int ri = 0; ri < 4; ++ri) hv[ri] = f2h(acc[mf][nf][ri] + bv);
        const size_t idx = ((size_t)(bb * HEADS + h) * HD + d) * NSEQ + n;
        *(ushort4*)(vt_out + idx) = *(ushort4*)hv;
      }
    }
  }
}

// ---------------------------------------------------------------------------
// Flash attention, single-f16 core with fixed-max softmax (R16, unchanged).
// 16 q-rows/wave, grid (16,12,4). Output: osp f16.
// ---------------------------------------------------------------------------
__global__ __launch_bounds__(256) void attn_single_k(
    const unsigned short* __restrict__ q_, const unsigned short* __restrict__ kk_,
    const unsigned short* __restrict__ vt_,
    unsigned short* __restrict__ osp)
{
  __shared__ __attribute__((aligned(16))) unsigned char lds[33792];
  unsigned char* const ldsK = lds;
  unsigned char* const ldsV = lds + 8192;

  const int tid  = threadIdx.x;
  const int wave = tid >> 6;
  const int lane = tid & 63;

  int flat = blockIdx.x + 16 * blockIdx.y + 192 * blockIdx.z;
  flat = (flat & 7) * 96 + (flat >> 3);
  const int bxq = flat & 15;
  const int h = (flat >> 4) % 12;
  const int b = flat / 192;
  const int bh = b * HEADS + h;
  const int q0 = bxq * 64 + wave * 16;

  unsigned int* const ldsP = (unsigned int*)(lds + 16384) + wave * (16 * 68);
  const int arow = lane & 15;
  const int agrp = lane >> 4;

  f16x8 q8[2];
  {
    const unsigned short* qp = q_ + ((size_t)bh * NSEQ + q0 + arow) * HD + agrp * 8;
    q8[0] = *(const f16x8*)qp;
    q8[1] = *(const f16x8*)(qp + 32);
  }

  f32x4 acc[4];
#pragma unroll
  for (int i = 0; i < 4; ++i) acc[i] = f32x4{0.f, 0.f, 0.f, 0.f};
  float l_run[4] = {0.f, 0.f, 0.f, 0.f};

  const int sr = tid >> 3, sc = tid & 7;
  const int swzc = ((sc ^ (sr & 7)) << 3);
  const size_t kbase = (size_t)bh * NSEQ * HD;
  const size_t vbase = (size_t)bh * HD * NSEQ;
  const unsigned short* gK = kk_ + kbase + (size_t)sr * 64 + swzc;
  const unsigned short* gV = vt_ + vbase + (size_t)sr * NSEQ + swzc;
  const int ldsw = (wave * 8) * 128;

  for (int j0 = 0; j0 < NSEQ; j0 += 64) {
    __syncthreads();
    gl16(gK + j0 * 64, ldsK + ldsw);
    gl16(gK + j0 * 64 + 2048, ldsK + ldsw + 4096);
    gl16(gV + j0, ldsV + ldsw);
    gl16(gV + j0 + 32 * NSEQ, ldsV + ldsw + 4096);
    __syncthreads();

    f32x4 s[4];
#pragma unroll
    for (int nt = 0; nt < 4; ++nt) s[nt] = f32x4{0.f, 0.f, 0.f, 0.f};
#pragma unroll
    for (int ks = 0; ks < 2; ++ks) {
#pragma unroll
      for (int nt = 0; nt < 4; ++nt) {
        const int krow = nt * 16 + arow;
        const int chunk = ks * 4 + agrp;
        const int off = krow * 128 + (((chunk ^ (krow & 7)) << 4));
        f16x8 kf = *(const f16x8*)(ldsK + off);
        s[nt] = __builtin_amdgcn_mfma_f32_16x16x32_f16(q8[ks], kf, s[nt], 0, 0, 0);
      }
    }

#pragma unroll
    for (int nt = 0; nt < 4; ++nt) {
#pragma unroll
      for (int r = 0; r < 4; ++r) {
        float p = __expf(s[nt][r]);
        l_run[r] += p;
        ldsP[(agrp * 4 + r) * 68 + nt * 16 + arow] = (unsigned int)f2h(p);
      }
    }

#pragma unroll
    for (int kk = 0; kk < 2; ++kk) {
      const unsigned int* prow = ldsP + arow * 68 + kk * 32 + agrp * 8;
      u32x4v w0 = *(const u32x4v*)prow;
      u32x4v w1 = *(const u32x4v*)(prow + 4);
      bf16x8 raw;
#pragma unroll
      for (int i = 0; i < 4; ++i) {
        raw[i]     = (short)(w0[i] & 0xffffu);
        raw[4 + i] = (short)(w1[i] & 0xffffu);
      }
      f16x8 p8 = *reinterpret_cast<f16x8*>(&raw);
#pragma unroll
      for (int nt2 = 0; nt2 < 4; ++nt2) {
        const int vrow = nt2 * 16 + arow;
        const int chunk = kk * 4 + agrp;
        const int off = vrow * 128 + (((chunk ^ (vrow & 7)) << 4));
        f16x8 vf = *(const f16x8*)(ldsV + off);
        acc[nt2] = __builtin_amdgcn_mfma_f32_16x16x32_f16(p8, vf, acc[nt2], 0, 0, 0);
      }
    }
  }

#pragma unroll
  for (int r = 0; r < 4; ++r) {
    float sm = l_run[r];
    sm += __shfl_xor(sm, 1, 64);
    sm += __shfl_xor(sm, 2, 64);
    sm += __shfl_xor(sm, 4, 64);
    sm += __shfl_xor(sm, 8, 64);
    const float inv = 1.f / sm;
    const int n = q0 + agrp * 4 + r;
    const size_t obase = ((size_t)(b * NSEQ + n)) * C_DIM + h * HD + arow;
#pragma unroll
    for (int nt2 = 0; nt2 < 4; ++nt2)
      osp[obase + nt2 * 16] = f2h(acc[nt2][r] * inv);
  }
}

// ---------------------------------------------------------------------------
// Fused attention (steps 4+5): shared QK^T + exp, two PV passes (R16).
// ---------------------------------------------------------------------------
__global__ __launch_bounds__(256) void attn_fused_k(
    const unsigned short* __restrict__ q_, const unsigned short* __restrict__ kk_,
    const unsigned short* __restrict__ vA_, const unsigned short* __restrict__ vB_,
    float* __restrict__ out1,
    unsigned short* __restrict__ osp)
{
  __shared__ __attribute__((aligned(16))) unsigned char lds[41984];
  unsigned char* const ldsK = lds;
  unsigned char* const ldsA = lds + 8192;
  unsigned char* const ldsB = lds + 16384;

  const int tid  = threadIdx.x;
  const int wave = tid >> 6;
  const int lane = tid & 63;

  int flat = blockIdx.x + 16 * blockIdx.y + 192 * blockIdx.z;
  flat = (flat & 7) * 96 + (flat >> 3);
  const int bxq = flat & 15;
  const int h = (flat >> 4) % 12;
  const int b = flat / 192;
  const int bh = b * HEADS + h;
  const int q0 = bxq * 64 + wave * 16;

  unsigned int* const ldsP = (unsigned int*)(lds + 24576) + wave * (16 * 68);
  const int arow = lane & 15;
  const int agrp = lane >> 4;

  f16x8 q8[2];
  {
    const unsigned short* qp = q_ + ((size_t)bh * NSEQ + q0 + arow) * HD + agrp * 8;
    q8[0] = *(const f16x8*)qp;
    q8[1] = *(const f16x8*)(qp + 32);
  }

  f32x4 acc1[4], acc2[4];
#pragma unroll
  for (int i = 0; i < 4; ++i) {
    acc1[i] = f32x4{0.f, 0.f, 0.f, 0.f};
    acc2[i] = f32x4{0.f, 0.f, 0.f, 0.f};
  }
  float l_run[4] = {0.f, 0.f, 0.f, 0.f};

  const int sr = tid >> 3, sc = tid & 7;
  const int swzc = ((sc ^ (sr & 7)) << 3);
  const size_t kbase = (size_t)bh * NSEQ * HD;
  const size_t vbase = (size_t)bh * HD * NSEQ;
  const unsigned short* gK = kk_ + kbase + (size_t)sr * 64 + swzc;
  const unsigned short* gA = vA_ + vbase + (size_t)sr * NSEQ + swzc;
  const unsigned short* gB = vB_ + vbase + (size_t)sr * NSEQ + swzc;
  const int ldsw = (wave * 8) * 128;

  for (int j0 = 0; j0 < NSEQ; j0 += 64) {
    __syncthreads();
    gl16(gK + j0 * 64, ldsK + ldsw);
    gl16(gK + j0 * 64 + 2048, ldsK + ldsw + 4096);
    gl16(gA + j0, ldsA + ldsw);
    gl16(gA + j0 + 32 * NSEQ, ldsA + ldsw + 4096);
    gl16(gB + j0, ldsB + ldsw);
    gl16(gB + j0 + 32 * NSEQ, ldsB + ldsw + 4096);
    __syncthreads();

    f32x4 s[4];
#pragma unroll
    for (int nt = 0; nt < 4; ++nt) s[nt] = f32x4{0.f, 0.f, 0.f, 0.f};
#pragma unroll
    for (int ks = 0; ks < 2; ++ks) {
#pragma unroll
      for (int nt = 0; nt < 4; ++nt) {
        const int krow = nt * 16 + arow;
        const int chunk = ks * 4 + agrp;
        const int off = krow * 128 + (((chunk ^ (krow & 7)) << 4));
        f16x8 kf = *(const f16x8*)(ldsK + off);
        s[nt] = __builtin_amdgcn_mfma_f32_16x16x32_f16(q8[ks], kf, s[nt], 0, 0, 0);
      }
    }

#pragma unroll
    for (int nt = 0; nt < 4; ++nt) {
#pragma unroll
      for (int r = 0; r < 4; ++r) {
        float p = __expf(s[nt][r]);
        l_run[r] += p;
        ldsP[(agrp * 4 + r) * 68 + nt * 16 + arow] = (unsigned int)f2h(p);
      }
    }

#pragma unroll
    for (int kk = 0; kk < 2; ++kk) {
      const unsigned int* prow = ldsP + arow * 68 + kk * 32 + agrp * 8;
      u32x4v w0 = *(const u32x4v*)prow;
      u32x4v w1 = *(const u32x4v*)(prow + 4);
      bf16x8 raw;
#pragma unroll
      for (int i = 0; i < 4; ++i) {
        raw[i]     = (short)(w0[i] & 0xffffu);
        raw[4 + i] = (short)(w1[i] & 0xffffu);
      }
      f16x8 p8 = *reinterpret_cast<f16x8*>(&raw);
#pragma unroll
      for (int nt2 = 0; nt2 < 4; ++nt2) {
        const int vrow = nt2 * 16 + arow;
        const int chunk = kk * 4 + agrp;
        const int off = vrow * 128 + (((chunk ^ (vrow & 7)) << 4));
        f16x8 va = *(const f16x8*)(ldsA + off);
        f16x8 vb = *(const f16x8*)(ldsB + off);
        acc1[nt2] = __builtin_amdgcn_mfma_f32_16x16x32_f16(p8, va, acc1[nt2], 0, 0, 0);
        acc2[nt2] = __builtin_amdgcn_mfma_f32_16x16x32_f16(p8, vb, acc2[nt2], 0, 0, 0);
      }
    }
  }

#pragma unroll
  for (int r = 0; r < 4; ++r) {
    float sm = l_run[r];
    sm += __shfl_xor(sm, 1, 64);
    sm += __shfl_xor(sm, 2, 64);
    sm += __shfl_xor(sm, 4, 64);
    sm += __shfl_xor(sm, 8, 64);
    const float inv = 1.f / sm;
    const int n = q0 + agrp * 4 + r;
    float* rowp = out1 + (size_t)b * (2048 * C_DIM) + (size_t)n * C_DIM + h * HD + arow;
    const size_t obase = ((size_t)(b * NSEQ + n)) * C_DIM + h * HD + arow;
#pragma unroll
    for (int nt2 = 0; nt2 < 4; ++nt2) {
      rowp[nt2 * 16] = acc1[nt2][r] * inv;
      osp[obase + nt2 * 16] = f2h(acc2[nt2][r] * inv);
    }
  }
}

// ---------------------------------------------------------------------------
extern "C" void kernel_launch(void* const* d_in, const int* in_sizes, int n_in,
                              void* d_out, int out_size, void* d_ws, size_t ws_size,
                              hipStream_t stream)
{
  const float* x           = (const float*)d_in[0];
  const float* w_qkv_diff  = (const float*)d_in[1];
  const float* w_qkv_cond  = (const float*)d_in[2];
  const float* w_proj_diff = (const float*)d_in[3];
  const float* b_proj_diff = (const float*)d_in[4];
  const float* w_proj_cond = (const float*)d_in[5];
  const float* b_proj_cond = (const float*)d_in[6];
  float* out = (float*)d_out;

  const size_t SZ = SZC;
  const size_t WQ = 2304 * 768;
  const size_t WP = 768 * 768;
  unsigned short* sw = (unsigned short*)d_ws;
  // qkv outputs (f16): per half: q, k, vt
  unsigned short* qd  = sw + 0 * SZ;
  unsigned short* kd  = sw + 1 * SZ;
  unsigned short* vtd = sw + 2 * SZ;
  unsigned short* qc  = sw + 3 * SZ;
  unsigned short* kc  = sw + 4 * SZ;
  unsigned short* vtc = sw + 5 * SZ;
  // weights (f16 single)
  unsigned short* wqdT = sw + 6 * SZ;
  unsigned short* wqcT = wqdT + WQ;
  unsigned short* wpdT = wqcT + WQ;
  unsigned short* wpcT = wpdT + WP;
  // osp (f16 single, SZ) after weights
  unsigned short* osp = wpcT + WP;
  // vt2 (f16 single, SZ) aliases qd (dead after step 2)
  unsigned short* vt2 = qd;
  // x f16 scratch: d_out (dead until step 4)
  unsigned short* xs = (unsigned short*)d_out;

  // 0. prep
  split_wT4_k<<<dim3(72, 24, 4), dim3(32, 8), 0, stream>>>(
      w_qkv_diff, w_qkv_cond, w_proj_diff, w_proj_cond,
      wqdT, wqcT, wpdT, wpcT);
  split_x_k<<<dim3(3072), 256, 0, stream>>>(x, xs);

  // 1. qkv both streams -> f16 q(/8, C^T epi), k (C^T epi), vt(T)
  gemm2_k<0><<<dim3(18, 32, 2), 256, 0, stream>>>(
      xs, wqdT, wqcT, nullptr, sw, nullptr, nullptr);

  // 2. attn_diff -> osp f16
  attn_single_k<<<dim3(16, 12, 4), 256, 0, stream>>>(qd, kd, vtd, osp);

  // 3. (osp @ w_proj_diff + b)^T -> vt2 f16
  gemm2_k<2><<<dim3(6, 32), 256, 0, stream>>>(
      osp, wpdT, nullptr, b_proj_diff, nullptr, nullptr, vt2);

  // 4+5. fused attn_cond: P @ vt2 -> out[:, :N] fp32 ; P @ vtc -> osp f16
  attn_fused_k<<<dim3(16, 12, 4), 256, 0, stream>>>(
      qc, kc, vt2, vtc, out, osp);

  // 6. out[:, N:] = osp @ w_proj_cond + b
  gemm2_k<1><<<dim3(6, 32), 256, 0, stream>>>(
      osp, wpcT, nullptr, b_proj_cond, nullptr, out, nullptr);
}

// Round 21
// 171.730 us; speedup vs baseline: 1.0011x; 1.0011x over previous
//
#include <hip/hip_runtime.h>
#include <hip/hip_bf16.h>

// B=4, N0=2048 (N=1024 diff + 1024 cond), C=768, H=12, hd=64. All fp32 I/O.
// SINGLE f16 everywhere (R13-R15); fixed-max softmax (R16).
// R21 = R20 with the compile fix: __builtin_exp2f (not __exp2f).
// R16 structure (best known: 166us, qkv 56us @ VGPR60) + log2e folded into
// q scale -> attn uses exp2 (saves the v_mul in every exp's range reduction).
//   0. prep: wT f16 (1 launch); x f16 -> d_out scratch
//   1. qkv [f16 MFMA] -> q f16 *(log2e/8), k f16, vt f16 (B,H,64,N)
//   2. osp = attn(q_d,k_d,vt_d)  [f16 MFMA] -> osp f16 (B*N,768)
//   3. vt2 = (osp @ w_proj_diff + b)^T  [f16 MFMA] -> f16 (B,H,64,N)
//   4+5 fused: P = exp2(q_c k_c^T) once;
//        out[:, :N] = P @ vt2 / l (fp32), osp = P @ vt_c / l (f16)
//   6. out[:, N:] = osp @ w_proj_cond + b   [f16 MFMA]
// Lessons held: MFMA operands from LDS (R9); many small attn blocks (R10);
// no setprio/defer-max in lockstep attn (R11); occupancy > pipeline depth at
// 128^2 (R6/R17); single launch > split (R18); no dual-MFMA branch (R19).

#define C_DIM 768
#define HEADS 12
#define HD 64
#define NSEQ 1024
#define BATCH 4
#define SZC 3145728  // BATCH*HEADS*NSEQ*HD

typedef short bf16x8 __attribute__((ext_vector_type(8)));       // raw 16-bit x8
typedef _Float16 f16x8 __attribute__((ext_vector_type(8)));
typedef float f32x4 __attribute__((ext_vector_type(4)));
typedef unsigned int u32x4v __attribute__((ext_vector_type(4)));

typedef __attribute__((address_space(3))) unsigned int lds_u32_t;
typedef __attribute__((address_space(1))) const unsigned int glb_u32_t;

__device__ __forceinline__ void gl16(const void* g, void* l) {
  __builtin_amdgcn_global_load_lds((glb_u32_t*)g, (lds_u32_t*)l, 16, 0, 0);
}

__device__ __forceinline__ unsigned short f2h(float x) {
  _Float16 h = (_Float16)x;
  return *reinterpret_cast<unsigned short*>(&h);
}

// ---------------------------------------------------------------------------
// Merged weight prep: 4 weights -> wT f16 single, z selects.
// ---------------------------------------------------------------------------
__global__ __launch_bounds__(256) void split_wT4_k(
    const float* __restrict__ w0, const float* __restrict__ w1,
    const float* __restrict__ w2, const float* __restrict__ w3,
    unsigned short* __restrict__ t0, unsigned short* __restrict__ t1,
    unsigned short* __restrict__ t2, unsigned short* __restrict__ t3)
{
  const int z = blockIdx.z;
  const int N = (z < 2) ? 2304 : 768;
  if (blockIdx.x * 32 >= N) return;
  const float* w = (z == 0) ? w0 : (z == 1) ? w1 : (z == 2) ? w2 : w3;
  unsigned short* th = (z == 0) ? t0 : (z == 1) ? t1 : (z == 2) ? t2 : t3;

  __shared__ float T[32][33];
  const int n0 = blockIdx.x * 32, k0 = blockIdx.y * 32;
  const int tx = threadIdx.x, ty = threadIdx.y;
#pragma unroll
  for (int i = 0; i < 4; ++i) {
    int k = ty + i * 8;
    T[k][tx] = w[(size_t)(k0 + k) * N + n0 + tx];
  }
  __syncthreads();
#pragma unroll
  for (int i = 0; i < 4; ++i) {
    int n = ty + i * 8;
    th[(size_t)(n0 + n) * 768 + k0 + tx] = f2h(T[tx][n]);
  }
}

// ---------------------------------------------------------------------------
// x prep: elementwise f16 convert of x -> xs.
// ---------------------------------------------------------------------------
__global__ __launch_bounds__(256) void split_x_k(
    const float* __restrict__ x, unsigned short* __restrict__ xs)
{
  const size_t i = ((size_t)blockIdx.x * 256 + threadIdx.x) * 8;
  float4 f0 = *(const float4*)(x + i);
  float4 f1 = *(const float4*)(x + i + 4);
  float fa[8] = {f0.x, f0.y, f0.z, f0.w, f1.x, f1.y, f1.z, f1.w};
  unsigned short hv[8];
#pragma unroll
  for (int j = 0; j < 8; ++j) hv[j] = f2h(fa[j]);
  *(bf16x8*)(xs + i) = *(bf16x8*)hv;
}

// ---------------------------------------------------------------------------
// Unified single-f16 GEMM: A f16, B f16, 1 MFMA/product. 2-phase dbuf,
// all-gl16 (pre-swizzled sources, chunk^((row>>1)&3)). 128x128 tile, BK=32,
// 4 waves, LDS 32 KB (16 KB/buffer). (R16 structure — proven best)
// EPI 0: qkv -> q f16 (x log2e/8), k f16, vt f16 transposed.
// EPI 1: proj -> fp32 d_out[:, N:] + bias.
// EPI 2: proj -> vt2 f16 transposed + bias.
// ---------------------------------------------------------------------------
template <int EPI>
__global__ __launch_bounds__(256) void gemm2_k(
    const unsigned short* __restrict__ A,
    const unsigned short* __restrict__ B0, const unsigned short* __restrict__ B1,
    const float* __restrict__ bias,
    unsigned short* __restrict__ ws_split,
    float* __restrict__ outf,
    unsigned short* __restrict__ vt_out)
{
  __shared__ __attribute__((aligned(16))) unsigned short lds[16384];  // 32 KB

  const int tid = threadIdx.x;
  const int lane = tid & 63;
  const int wave = tid >> 6;
  const int wr = wave >> 1, wc = wave & 1;
  const int arow = lane & 15, agrp = lane >> 4;

  int bx, by, half;
  if constexpr (EPI == 0) {
    int orig = blockIdx.x + 18 * blockIdx.y + 576 * blockIdx.z;  // [0,1152)
    int xcd = orig & 7, l = orig >> 3;
    int g = xcd * 6 + (l / 24);
    int r = l % 24;
    int rest = g / 6;
    bx = (g % 6) * 3 + (r % 3);
    by = (rest & 3) * 8 + (r / 3);
    half = rest >> 2;
  } else {
    int flat = blockIdx.x + 6 * blockIdx.y;  // nwg = 192
    flat = (flat & 7) * 24 + (flat >> 3);
    bx = flat % 6;
    by = flat / 6;
    half = 0;
  }

  const int m0 = by * 128;
  const int b = m0 >> 10, nloc = m0 & 1023;
  const int c0 = bx * 128;
  const unsigned short* __restrict__ Bp = (EPI == 0 && half) ? B1 : B0;
  const size_t Arow = (EPI == 0) ? (size_t)(b * 2048 + half * 1024 + nloc)
                                 : (size_t)m0;

  const int gr = tid >> 2, gc = (tid & 3) ^ ((tid >> 3) & 3);
  const unsigned short* gA = A + (Arow + gr) * 768 + gc * 8;
  const unsigned short* gB = Bp + (size_t)(c0 + gr) * 768 + gc * 8;
  const int wo = wave * 512;

  f32x4 acc[4][4];
#pragma unroll
  for (int i = 0; i < 4; ++i)
#pragma unroll
    for (int j = 0; j < 4; ++j) acc[i][j] = f32x4{0.f, 0.f, 0.f, 0.f};

  auto stage4 = [&](int k0, int bo) {
    gl16(gA + k0, lds + bo + wo);
    gl16(gA + k0 + 64 * 768, lds + bo + wo + 2048);
    gl16(gB + k0, lds + bo + 4096 + wo);
    gl16(gB + k0 + 64 * 768, lds + bo + 4096 + wo + 2048);
  };

  stage4(0, 0);
  asm volatile("s_waitcnt vmcnt(0)" ::: "memory");
  __builtin_amdgcn_s_barrier();

  int cur = 0;
  for (int t = 0; t < 24; ++t) {
    const int bo = cur * 8192;
    if (t < 23) stage4((t + 1) * 32, bo ^ 8192);

    f16x8 af[4], bf[4];
#pragma unroll
    for (int mf = 0; mf < 4; ++mf) {
      const int row = wr * 64 + mf * 16 + arow;
      const int off = bo + row * 32 + ((agrp ^ ((row >> 1) & 3)) << 3);
      af[mf] = *(const f16x8*)(lds + off);
    }
#pragma unroll
    for (int nf = 0; nf < 4; ++nf) {
      const int row = wc * 64 + nf * 16 + arow;
      const int off = bo + row * 32 + ((agrp ^ ((row >> 1) & 3)) << 3);
      bf[nf] = *(const f16x8*)(lds + 4096 + off);
    }
#pragma unroll
    for (int mf = 0; mf < 4; ++mf)
#pragma unroll
      for (int nf = 0; nf < 4; ++nf)
        acc[mf][nf] = __builtin_amdgcn_mfma_f32_16x16x32_f16(af[mf], bf[nf], acc[mf][nf], 0, 0, 0);

    if (t < 23) {
      asm volatile("s_waitcnt vmcnt(0)" ::: "memory");
      __builtin_amdgcn_s_barrier();
      cur ^= 1;
    }
  }

  if constexpr (EPI == 0) {
    // arrays per half: 0=q (f16, x log2e/8), 1=k (f16), 2=vt (f16, T)
    const int t_ = c0 / 768;
    const int rem0 = c0 - t_ * 768;
    unsigned short* base = ws_split + (size_t)(half * 3) * SZC;
    const float qs = (t_ == 0) ? (0.125f * 1.44269504089f) : 1.0f;
#pragma unroll
    for (int nf = 0; nf < 4; ++nf) {
      const int rc = rem0 + wc * 64 + nf * 16 + arow;
      const int h = rc >> 6;
      const int d = rc & 63;
      const size_t bh_ = (size_t)(b * HEADS + h);
      if (t_ < 2) {
        unsigned short* arr = base + (size_t)t_ * SZC;
#pragma unroll
        for (int mf = 0; mf < 4; ++mf) {
#pragma unroll
          for (int ri = 0; ri < 4; ++ri) {
            const int n = nloc + wr * 64 + mf * 16 + agrp * 4 + ri;
            arr[(bh_ * NSEQ + n) * HD + d] = f2h(acc[mf][nf][ri] * qs);
          }
        }
      } else {
        unsigned short* vt_a = base + 2 * (size_t)SZC;
#pragma unroll
        for (int mf = 0; mf < 4; ++mf) {
          const int n = nloc + wr * 64 + mf * 16 + agrp * 4;
          unsigned short hv[4];
#pragma unroll
          for (int ri = 0; ri < 4; ++ri) hv[ri] = f2h(acc[mf][nf][ri]);
          *(ushort4*)(vt_a + (bh_ * HD + d) * NSEQ + n) = *(ushort4*)hv;
        }
      }
    }
  } else if constexpr (EPI == 1) {
#pragma unroll
    for (int nf = 0; nf < 4; ++nf) {
      const int cg = c0 + wc * 64 + nf * 16 + arow;
      const float bv = bias[cg];
#pragma unroll
      for (int mf = 0; mf < 4; ++mf) {
#pragma unroll
        for (int ri = 0; ri < 4; ++ri) {
          const int m = m0 + wr * 64 + mf * 16 + agrp * 4 + ri;
          const int bb = m >> 10, n = m & 1023;
          outf[(size_t)bb * (2048 * 768) + (size_t)(1024 + n) * 768 + cg] =
              acc[mf][nf][ri] + bv;
        }
      }
    }
  } else {  // EPI == 2: f16 transposed (B,H,64,N)
#pragma unroll
    for (int nf = 0; nf < 4; ++nf) {
      const int cg = c0 + wc * 64 + nf * 16 + arow;
      const int h = cg >> 6, d = cg & 63;
      const float bv = bias[cg];
#pragma unroll
      for (int mf = 0; mf < 4; ++mf) {
        const int m = m0 + wr * 64 + mf * 16 + agrp * 4;
        const int bb = m >> 10, n = m & 1023;
        unsigned short hv[4];
#pragma unroll
        for (int ri = 0; ri < 4; ++ri) hv[ri] = f2h(acc[mf][nf][ri] + bv);
        const size_t idx = ((size_t)(bb * HEADS + h) * HD + d) * NSEQ + n;
        *(ushort4*)(vt_out + idx) = *(ushort4*)hv;
      }
    }
  }
}

// ---------------------------------------------------------------------------
// Flash attention, single-f16 core, fixed-max softmax with exp2 (q carries
// log2e/8): P = exp2(S'), l per-lane, one reduction at the end.
// 16 q-rows/wave, grid (16,12,4). Output: osp f16.
// ---------------------------------------------------------------------------
__global__ __launch_bounds__(256) void attn_single_k(
    const unsigned short* __restrict__ q_, const unsigned short* __restrict__ kk_,
    const unsigned short* __restrict__ vt_,
    unsigned short* __restrict__ osp)
{
  __shared__ __attribute__((aligned(16))) unsigned char lds[33792];
  unsigned char* const ldsK = lds;
  unsigned char* const ldsV = lds + 8192;

  const int tid  = threadIdx.x;
  const int wave = tid >> 6;
  const int lane = tid & 63;

  int flat = blockIdx.x + 16 * blockIdx.y + 192 * blockIdx.z;
  flat = (flat & 7) * 96 + (flat >> 3);
  const int bxq = flat & 15;
  const int h = (flat >> 4) % 12;
  const int b = flat / 192;
  const int bh = b * HEADS + h;
  const int q0 = bxq * 64 + wave * 16;

  unsigned int* const ldsP = (unsigned int*)(lds + 16384) + wave * (16 * 68);
  const int arow = lane & 15;
  const int agrp = lane >> 4;

  f16x8 q8[2];
  {
    const unsigned short* qp = q_ + ((size_t)bh * NSEQ + q0 + arow) * HD + agrp * 8;
    q8[0] = *(const f16x8*)qp;
    q8[1] = *(const f16x8*)(qp + 32);
  }

  f32x4 acc[4];
#pragma unroll
  for (int i = 0; i < 4; ++i) acc[i] = f32x4{0.f, 0.f, 0.f, 0.f};
  float l_run[4] = {0.f, 0.f, 0.f, 0.f};

  const int sr = tid >> 3, sc = tid & 7;
  const int swzc = ((sc ^ (sr & 7)) << 3);
  const size_t kbase = (size_t)bh * NSEQ * HD;
  const size_t vbase = (size_t)bh * HD * NSEQ;
  const unsigned short* gK = kk_ + kbase + (size_t)sr * 64 + swzc;
  const unsigned short* gV = vt_ + vbase + (size_t)sr * NSEQ + swzc;
  const int ldsw = (wave * 8) * 128;

  for (int j0 = 0; j0 < NSEQ; j0 += 64) {
    __syncthreads();
    gl16(gK + j0 * 64, ldsK + ldsw);
    gl16(gK + j0 * 64 + 2048, ldsK + ldsw + 4096);
    gl16(gV + j0, ldsV + ldsw);
    gl16(gV + j0 + 32 * NSEQ, ldsV + ldsw + 4096);
    __syncthreads();

    f32x4 s[4];
#pragma unroll
    for (int nt = 0; nt < 4; ++nt) s[nt] = f32x4{0.f, 0.f, 0.f, 0.f};
#pragma unroll
    for (int ks = 0; ks < 2; ++ks) {
#pragma unroll
      for (int nt = 0; nt < 4; ++nt) {
        const int krow = nt * 16 + arow;
        const int chunk = ks * 4 + agrp;
        const int off = krow * 128 + (((chunk ^ (krow & 7)) << 4));
        f16x8 kf = *(const f16x8*)(ldsK + off);
        s[nt] = __builtin_amdgcn_mfma_f32_16x16x32_f16(q8[ks], kf, s[nt], 0, 0, 0);
      }
    }

    // fixed-max softmax: P = exp2(S') (log2e pre-folded into q)
#pragma unroll
    for (int nt = 0; nt < 4; ++nt) {
#pragma unroll
      for (int r = 0; r < 4; ++r) {
        float p = __builtin_exp2f(s[nt][r]);
        l_run[r] += p;
        ldsP[(agrp * 4 + r) * 68 + nt * 16 + arow] = (unsigned int)f2h(p);
      }
    }

#pragma unroll
    for (int kk = 0; kk < 2; ++kk) {
      const unsigned int* prow = ldsP + arow * 68 + kk * 32 + agrp * 8;
      u32x4v w0 = *(const u32x4v*)prow;
      u32x4v w1 = *(const u32x4v*)(prow + 4);
      bf16x8 raw;
#pragma unroll
      for (int i = 0; i < 4; ++i) {
        raw[i]     = (short)(w0[i] & 0xffffu);
        raw[4 + i] = (short)(w1[i] & 0xffffu);
      }
      f16x8 p8 = *reinterpret_cast<f16x8*>(&raw);
#pragma unroll
      for (int nt2 = 0; nt2 < 4; ++nt2) {
        const int vrow = nt2 * 16 + arow;
        const int chunk = kk * 4 + agrp;
        const int off = vrow * 128 + (((chunk ^ (vrow & 7)) << 4));
        f16x8 vf = *(const f16x8*)(ldsV + off);
        acc[nt2] = __builtin_amdgcn_mfma_f32_16x16x32_f16(p8, vf, acc[nt2], 0, 0, 0);
      }
    }
  }

#pragma unroll
  for (int r = 0; r < 4; ++r) {
    float sm = l_run[r];
    sm += __shfl_xor(sm, 1, 64);
    sm += __shfl_xor(sm, 2, 64);
    sm += __shfl_xor(sm, 4, 64);
    sm += __shfl_xor(sm, 8, 64);
    const float inv = 1.f / sm;
    const int n = q0 + agrp * 4 + r;
    const size_t obase = ((size_t)(b * NSEQ + n)) * C_DIM + h * HD + arow;
#pragma unroll
    for (int nt2 = 0; nt2 < 4; ++nt2)
      osp[obase + nt2 * 16] = f2h(acc[nt2][r] * inv);
  }
}

// ---------------------------------------------------------------------------
// Fused attention (steps 4+5): shared QK^T + exp2, two PV passes.
// ---------------------------------------------------------------------------
__global__ __launch_bounds__(256) void attn_fused_k(
    const unsigned short* __restrict__ q_, const unsigned short* __restrict__ kk_,
    const unsigned short* __restrict__ vA_, const unsigned short* __restrict__ vB_,
    float* __restrict__ out1,
    unsigned short* __restrict__ osp)
{
  __shared__ __attribute__((aligned(16))) unsigned char lds[41984];
  unsigned char* const ldsK = lds;
  unsigned char* const ldsA = lds + 8192;
  unsigned char* const ldsB = lds + 16384;

  const int tid  = threadIdx.x;
  const int wave = tid >> 6;
  const int lane = tid & 63;

  int flat = blockIdx.x + 16 * blockIdx.y + 192 * blockIdx.z;
  flat = (flat & 7) * 96 + (flat >> 3);
  const int bxq = flat & 15;
  const int h = (flat >> 4) % 12;
  const int b = flat / 192;
  const int bh = b * HEADS + h;
  const int q0 = bxq * 64 + wave * 16;

  unsigned int* const ldsP = (unsigned int*)(lds + 24576) + wave * (16 * 68);
  const int arow = lane & 15;
  const int agrp = lane >> 4;

  f16x8 q8[2];
  {
    const unsigned short* qp = q_ + ((size_t)bh * NSEQ + q0 + arow) * HD + agrp * 8;
    q8[0] = *(const f16x8*)qp;
    q8[1] = *(const f16x8*)(qp + 32);
  }

  f32x4 acc1[4], acc2[4];
#pragma unroll
  for (int i = 0; i < 4; ++i) {
    acc1[i] = f32x4{0.f, 0.f, 0.f, 0.f};
    acc2[i] = f32x4{0.f, 0.f, 0.f, 0.f};
  }
  float l_run[4] = {0.f, 0.f, 0.f, 0.f};

  const int sr = tid >> 3, sc = tid & 7;
  const int swzc = ((sc ^ (sr & 7)) << 3);
  const size_t kbase = (size_t)bh * NSEQ * HD;
  const size_t vbase = (size_t)bh * HD * NSEQ;
  const unsigned short* gK = kk_ + kbase + (size_t)sr * 64 + swzc;
  const unsigned short* gA = vA_ + vbase + (size_t)sr * NSEQ + swzc;
  const unsigned short* gB = vB_ + vbase + (size_t)sr * NSEQ + swzc;
  const int ldsw = (wave * 8) * 128;

  for (int j0 = 0; j0 < NSEQ; j0 += 64) {
    __syncthreads();
    gl16(gK + j0 * 64, ldsK + ldsw);
    gl16(gK + j0 * 64 + 2048, ldsK + ldsw + 4096);
    gl16(gA + j0, ldsA + ldsw);
    gl16(gA + j0 + 32 * NSEQ, ldsA + ldsw + 4096);
    gl16(gB + j0, ldsB + ldsw);
    gl16(gB + j0 + 32 * NSEQ, ldsB + ldsw + 4096);
    __syncthreads();

    f32x4 s[4];
#pragma unroll
    for (int nt = 0; nt < 4; ++nt) s[nt] = f32x4{0.f, 0.f, 0.f, 0.f};
#pragma unroll
    for (int ks = 0; ks < 2; ++ks) {
#pragma unroll
      for (int nt = 0; nt < 4; ++nt) {
        const int krow = nt * 16 + arow;
        const int chunk = ks * 4 + agrp;
        const int off = krow * 128 + (((chunk ^ (krow & 7)) << 4));
        f16x8 kf = *(const f16x8*)(ldsK + off);
        s[nt] = __builtin_amdgcn_mfma_f32_16x16x32_f16(q8[ks], kf, s[nt], 0, 0, 0);
      }
    }

#pragma unroll
    for (int nt = 0; nt < 4; ++nt) {
#pragma unroll
      for (int r = 0; r < 4; ++r) {
        float p = __builtin_exp2f(s[nt][r]);
        l_run[r] += p;
        ldsP[(agrp * 4 + r) * 68 + nt * 16 + arow] = (unsigned int)f2h(p);
      }
    }

#pragma unroll
    for (int kk = 0; kk < 2; ++kk) {
      const unsigned int* prow = ldsP + arow * 68 + kk * 32 + agrp * 8;
      u32x4v w0 = *(const u32x4v*)prow;
      u32x4v w1 = *(const u32x4v*)(prow + 4);
      bf16x8 raw;
#pragma unroll
      for (int i = 0; i < 4; ++i) {
        raw[i]     = (short)(w0[i] & 0xffffu);
        raw[4 + i] = (short)(w1[i] & 0xffffu);
      }
      f16x8 p8 = *reinterpret_cast<f16x8*>(&raw);
#pragma unroll
      for (int nt2 = 0; nt2 < 4; ++nt2) {
        const int vrow = nt2 * 16 + arow;
        const int chunk = kk * 4 + agrp;
        const int off = vrow * 128 + (((chunk ^ (vrow & 7)) << 4));
        f16x8 va = *(const f16x8*)(ldsA + off);
        f16x8 vb = *(const f16x8*)(ldsB + off);
        acc1[nt2] = __builtin_amdgcn_mfma_f32_16x16x32_f16(p8, va, acc1[nt2], 0, 0, 0);
        acc2[nt2] = __builtin_amdgcn_mfma_f32_16x16x32_f16(p8, vb, acc2[nt2], 0, 0, 0);
      }
    }
  }

#pragma unroll
  for (int r = 0; r < 4; ++r) {
    float sm = l_run[r];
    sm += __shfl_xor(sm, 1, 64);
    sm += __shfl_xor(sm, 2, 64);
    sm += __shfl_xor(sm, 4, 64);
    sm += __shfl_xor(sm, 8, 64);
    const float inv = 1.f / sm;
    const int n = q0 + agrp * 4 + r;
    float* rowp = out1 + (size_t)b * (2048 * C_DIM) + (size_t)n * C_DIM + h * HD + arow;
    const size_t obase = ((size_t)(b * NSEQ + n)) * C_DIM + h * HD + arow;
#pragma unroll
    for (int nt2 = 0; nt2 < 4; ++nt2) {
      rowp[nt2 * 16] = acc1[nt2][r] * inv;
      osp[obase + nt2 * 16] = f2h(acc2[nt2][r] * inv);
    }
  }
}

// ---------------------------------------------------------------------------
extern "C" void kernel_launch(void* const* d_in, const int* in_sizes, int n_in,
                              void* d_out, int out_size, void* d_ws, size_t ws_size,
                              hipStream_t stream)
{
  const float* x           = (const float*)d_in[0];
  const float* w_qkv_diff  = (const float*)d_in[1];
  const float* w_qkv_cond  = (const float*)d_in[2];
  const float* w_proj_diff = (const float*)d_in[3];
  const float* b_proj_diff = (const float*)d_in[4];
  const float* w_proj_cond = (const float*)d_in[5];
  const float* b_proj_cond = (const float*)d_in[6];
  float* out = (float*)d_out;

  const size_t SZ = SZC;
  const size_t WQ = 2304 * 768;
  const size_t WP = 768 * 768;
  unsigned short* sw = (unsigned short*)d_ws;
  // qkv outputs (f16): per half: q, k, vt
  unsigned short* qd  = sw + 0 * SZ;
  unsigned short* kd  = sw + 1 * SZ;
  unsigned short* vtd = sw + 2 * SZ;
  unsigned short* qc  = sw + 3 * SZ;
  unsigned short* kc  = sw + 4 * SZ;
  unsigned short* vtc = sw + 5 * SZ;
  // weights (f16 single)
  unsigned short* wqdT = sw + 6 * SZ;
  unsigned short* wqcT = wqdT + WQ;
  unsigned short* wpdT = wqcT + WQ;
  unsigned short* wpcT = wpdT + WP;
  // osp (f16 single, SZ) after weights
  unsigned short* osp = wpcT + WP;
  // vt2 (f16 single, SZ) aliases qd (dead after step 2)
  unsigned short* vt2 = qd;
  // x f16 scratch: d_out (dead until step 4)
  unsigned short* xs = (unsigned short*)d_out;

  // 0. prep
  split_wT4_k<<<dim3(72, 24, 4), dim3(32, 8), 0, stream>>>(
      w_qkv_diff, w_qkv_cond, w_proj_diff, w_proj_cond,
      wqdT, wqcT, wpdT, wpcT);
  split_x_k<<<dim3(3072), 256, 0, stream>>>(x, xs);

  // 1. qkv both streams -> f16 q(x log2e/8), k, vt(T)
  gemm2_k<0><<<dim3(18, 32, 2), 256, 0, stream>>>(
      xs, wqdT, wqcT, nullptr, sw, nullptr, nullptr);

  // 2. attn_diff -> osp f16
  attn_single_k<<<dim3(16, 12, 4), 256, 0, stream>>>(qd, kd, vtd, osp);

  // 3. (osp @ w_proj_diff + b)^T -> vt2 f16
  gemm2_k<2><<<dim3(6, 32), 256, 0, stream>>>(
      osp, wpdT, nullptr, b_proj_diff, nullptr, nullptr, vt2);

  // 4+5. fused attn_cond: P @ vt2 -> out[:, :N] fp32 ; P @ vtc -> osp f16
  attn_fused_k<<<dim3(16, 12, 4), 256, 0, stream>>>(
      qc, kc, vt2, vtc, out, osp);

  // 6. out[:, N:] = osp @ w_proj_cond + b
  gemm2_k<1><<<dim3(6, 32), 256, 0, stream>>>(
      osp, wpcT, nullptr, b_proj_cond, nullptr, out, nullptr);
}

// Round 22
// 168.420 us; speedup vs baseline: 1.0207x; 1.0197x over previous
//
#include <hip/hip_runtime.h>
#include <hip/hip_bf16.h>

// B=4, N0=2048 (N=1024 diff + 1024 cond), C=768, H=12, hd=64. All fp32 I/O.
// SINGLE f16 everywhere (R13-R15); fixed-max softmax (R16); exp2 w/ log2e
// folded into q (R21). R22: P stored as PACKED ushort in LDS (stride 72) ->
// PV A-frag read is one aligned ds_read_b128 reinterpreted as f16x8 (was
// 8 u32 reads + 8 mask ops); P-LDS halves -> attn occupancy 4->6 / 3->4
// blocks/CU.
//   0. prep: wT f16 (1 launch); x f16 -> d_out scratch
//   1. qkv [f16 MFMA] -> q f16 *(log2e/8), k f16, vt f16 (B,H,64,N)
//   2. osp = attn(q_d,k_d,vt_d)  [f16 MFMA] -> osp f16 (B*N,768)
//   3. vt2 = (osp @ w_proj_diff + b)^T  [f16 MFMA] -> f16 (B,H,64,N)
//   4+5 fused: P = exp2(q_c k_c^T) once;
//        out[:, :N] = P @ vt2 / l (fp32), osp = P @ vt_c / l (f16)
//   6. out[:, N:] = osp @ w_proj_cond + b   [f16 MFMA]
// Lessons held: MFMA operands from LDS (R9); many small attn blocks (R10);
// no setprio/defer-max in lockstep attn (R11); occupancy > pipeline depth at
// 128^2 (R6/R17); single launch > split (R18); no dual-MFMA branch (R19).

#define C_DIM 768
#define HEADS 12
#define HD 64
#define NSEQ 1024
#define BATCH 4
#define SZC 3145728  // BATCH*HEADS*NSEQ*HD

typedef short bf16x8 __attribute__((ext_vector_type(8)));       // raw 16-bit x8
typedef _Float16 f16x8 __attribute__((ext_vector_type(8)));
typedef float f32x4 __attribute__((ext_vector_type(4)));
typedef unsigned int u32x4v __attribute__((ext_vector_type(4)));

typedef __attribute__((address_space(3))) unsigned int lds_u32_t;
typedef __attribute__((address_space(1))) const unsigned int glb_u32_t;

__device__ __forceinline__ void gl16(const void* g, void* l) {
  __builtin_amdgcn_global_load_lds((glb_u32_t*)g, (lds_u32_t*)l, 16, 0, 0);
}

__device__ __forceinline__ unsigned short f2h(float x) {
  _Float16 h = (_Float16)x;
  return *reinterpret_cast<unsigned short*>(&h);
}

// ---------------------------------------------------------------------------
// Merged weight prep: 4 weights -> wT f16 single, z selects.
// ---------------------------------------------------------------------------
__global__ __launch_bounds__(256) void split_wT4_k(
    const float* __restrict__ w0, const float* __restrict__ w1,
    const float* __restrict__ w2, const float* __restrict__ w3,
    unsigned short* __restrict__ t0, unsigned short* __restrict__ t1,
    unsigned short* __restrict__ t2, unsigned short* __restrict__ t3)
{
  const int z = blockIdx.z;
  const int N = (z < 2) ? 2304 : 768;
  if (blockIdx.x * 32 >= N) return;
  const float* w = (z == 0) ? w0 : (z == 1) ? w1 : (z == 2) ? w2 : w3;
  unsigned short* th = (z == 0) ? t0 : (z == 1) ? t1 : (z == 2) ? t2 : t3;

  __shared__ float T[32][33];
  const int n0 = blockIdx.x * 32, k0 = blockIdx.y * 32;
  const int tx = threadIdx.x, ty = threadIdx.y;
#pragma unroll
  for (int i = 0; i < 4; ++i) {
    int k = ty + i * 8;
    T[k][tx] = w[(size_t)(k0 + k) * N + n0 + tx];
  }
  __syncthreads();
#pragma unroll
  for (int i = 0; i < 4; ++i) {
    int n = ty + i * 8;
    th[(size_t)(n0 + n) * 768 + k0 + tx] = f2h(T[tx][n]);
  }
}

// ---------------------------------------------------------------------------
// x prep: elementwise f16 convert of x -> xs.
// ---------------------------------------------------------------------------
__global__ __launch_bounds__(256) void split_x_k(
    const float* __restrict__ x, unsigned short* __restrict__ xs)
{
  const size_t i = ((size_t)blockIdx.x * 256 + threadIdx.x) * 8;
  float4 f0 = *(const float4*)(x + i);
  float4 f1 = *(const float4*)(x + i + 4);
  float fa[8] = {f0.x, f0.y, f0.z, f0.w, f1.x, f1.y, f1.z, f1.w};
  unsigned short hv[8];
#pragma unroll
  for (int j = 0; j < 8; ++j) hv[j] = f2h(fa[j]);
  *(bf16x8*)(xs + i) = *(bf16x8*)hv;
}

// ---------------------------------------------------------------------------
// Unified single-f16 GEMM: A f16, B f16, 1 MFMA/product. 2-phase dbuf,
// all-gl16 (pre-swizzled sources, chunk^((row>>1)&3)). 128x128 tile, BK=32,
// 4 waves, LDS 32 KB (16 KB/buffer). (R16 structure — proven best)
// EPI 0: qkv -> q f16 (x log2e/8), k f16, vt f16 transposed.
// EPI 1: proj -> fp32 d_out[:, N:] + bias.
// EPI 2: proj -> vt2 f16 transposed + bias.
// ---------------------------------------------------------------------------
template <int EPI>
__global__ __launch_bounds__(256) void gemm2_k(
    const unsigned short* __restrict__ A,
    const unsigned short* __restrict__ B0, const unsigned short* __restrict__ B1,
    const float* __restrict__ bias,
    unsigned short* __restrict__ ws_split,
    float* __restrict__ outf,
    unsigned short* __restrict__ vt_out)
{
  __shared__ __attribute__((aligned(16))) unsigned short lds[16384];  // 32 KB

  const int tid = threadIdx.x;
  const int lane = tid & 63;
  const int wave = tid >> 6;
  const int wr = wave >> 1, wc = wave & 1;
  const int arow = lane & 15, agrp = lane >> 4;

  int bx, by, half;
  if constexpr (EPI == 0) {
    int orig = blockIdx.x + 18 * blockIdx.y + 576 * blockIdx.z;  // [0,1152)
    int xcd = orig & 7, l = orig >> 3;
    int g = xcd * 6 + (l / 24);
    int r = l % 24;
    int rest = g / 6;
    bx = (g % 6) * 3 + (r % 3);
    by = (rest & 3) * 8 + (r / 3);
    half = rest >> 2;
  } else {
    int flat = blockIdx.x + 6 * blockIdx.y;  // nwg = 192
    flat = (flat & 7) * 24 + (flat >> 3);
    bx = flat % 6;
    by = flat / 6;
    half = 0;
  }

  const int m0 = by * 128;
  const int b = m0 >> 10, nloc = m0 & 1023;
  const int c0 = bx * 128;
  const unsigned short* __restrict__ Bp = (EPI == 0 && half) ? B1 : B0;
  const size_t Arow = (EPI == 0) ? (size_t)(b * 2048 + half * 1024 + nloc)
                                 : (size_t)m0;

  const int gr = tid >> 2, gc = (tid & 3) ^ ((tid >> 3) & 3);
  const unsigned short* gA = A + (Arow + gr) * 768 + gc * 8;
  const unsigned short* gB = Bp + (size_t)(c0 + gr) * 768 + gc * 8;
  const int wo = wave * 512;

  f32x4 acc[4][4];
#pragma unroll
  for (int i = 0; i < 4; ++i)
#pragma unroll
    for (int j = 0; j < 4; ++j) acc[i][j] = f32x4{0.f, 0.f, 0.f, 0.f};

  auto stage4 = [&](int k0, int bo) {
    gl16(gA + k0, lds + bo + wo);
    gl16(gA + k0 + 64 * 768, lds + bo + wo + 2048);
    gl16(gB + k0, lds + bo + 4096 + wo);
    gl16(gB + k0 + 64 * 768, lds + bo + 4096 + wo + 2048);
  };

  stage4(0, 0);
  asm volatile("s_waitcnt vmcnt(0)" ::: "memory");
  __builtin_amdgcn_s_barrier();

  int cur = 0;
  for (int t = 0; t < 24; ++t) {
    const int bo = cur * 8192;
    if (t < 23) stage4((t + 1) * 32, bo ^ 8192);

    f16x8 af[4], bf[4];
#pragma unroll
    for (int mf = 0; mf < 4; ++mf) {
      const int row = wr * 64 + mf * 16 + arow;
      const int off = bo + row * 32 + ((agrp ^ ((row >> 1) & 3)) << 3);
      af[mf] = *(const f16x8*)(lds + off);
    }
#pragma unroll
    for (int nf = 0; nf < 4; ++nf) {
      const int row = wc * 64 + nf * 16 + arow;
      const int off = bo + row * 32 + ((agrp ^ ((row >> 1) & 3)) << 3);
      bf[nf] = *(const f16x8*)(lds + 4096 + off);
    }
#pragma unroll
    for (int mf = 0; mf < 4; ++mf)
#pragma unroll
      for (int nf = 0; nf < 4; ++nf)
        acc[mf][nf] = __builtin_amdgcn_mfma_f32_16x16x32_f16(af[mf], bf[nf], acc[mf][nf], 0, 0, 0);

    if (t < 23) {
      asm volatile("s_waitcnt vmcnt(0)" ::: "memory");
      __builtin_amdgcn_s_barrier();
      cur ^= 1;
    }
  }

  if constexpr (EPI == 0) {
    // arrays per half: 0=q (f16, x log2e/8), 1=k (f16), 2=vt (f16, T)
    const int t_ = c0 / 768;
    const int rem0 = c0 - t_ * 768;
    unsigned short* base = ws_split + (size_t)(half * 3) * SZC;
    const float qs = (t_ == 0) ? (0.125f * 1.44269504089f) : 1.0f;
#pragma unroll
    for (int nf = 0; nf < 4; ++nf) {
      const int rc = rem0 + wc * 64 + nf * 16 + arow;
      const int h = rc >> 6;
      const int d = rc & 63;
      const size_t bh_ = (size_t)(b * HEADS + h);
      if (t_ < 2) {
        unsigned short* arr = base + (size_t)t_ * SZC;
#pragma unroll
        for (int mf = 0; mf < 4; ++mf) {
#pragma unroll
          for (int ri = 0; ri < 4; ++ri) {
            const int n = nloc + wr * 64 + mf * 16 + agrp * 4 + ri;
            arr[(bh_ * NSEQ + n) * HD + d] = f2h(acc[mf][nf][ri] * qs);
          }
        }
      } else {
        unsigned short* vt_a = base + 2 * (size_t)SZC;
#pragma unroll
        for (int mf = 0; mf < 4; ++mf) {
          const int n = nloc + wr * 64 + mf * 16 + agrp * 4;
          unsigned short hv[4];
#pragma unroll
          for (int ri = 0; ri < 4; ++ri) hv[ri] = f2h(acc[mf][nf][ri]);
          *(ushort4*)(vt_a + (bh_ * HD + d) * NSEQ + n) = *(ushort4*)hv;
        }
      }
    }
  } else if constexpr (EPI == 1) {
#pragma unroll
    for (int nf = 0; nf < 4; ++nf) {
      const int cg = c0 + wc * 64 + nf * 16 + arow;
      const float bv = bias[cg];
#pragma unroll
      for (int mf = 0; mf < 4; ++mf) {
#pragma unroll
        for (int ri = 0; ri < 4; ++ri) {
          const int m = m0 + wr * 64 + mf * 16 + agrp * 4 + ri;
          const int bb = m >> 10, n = m & 1023;
          outf[(size_t)bb * (2048 * 768) + (size_t)(1024 + n) * 768 + cg] =
              acc[mf][nf][ri] + bv;
        }
      }
    }
  } else {  // EPI == 2: f16 transposed (B,H,64,N)
#pragma unroll
    for (int nf = 0; nf < 4; ++nf) {
      const int cg = c0 + wc * 64 + nf * 16 + arow;
      const int h = cg >> 6, d = cg & 63;
      const float bv = bias[cg];
#pragma unroll
      for (int mf = 0; mf < 4; ++mf) {
        const int m = m0 + wr * 64 + mf * 16 + agrp * 4;
        const int bb = m >> 10, n = m & 1023;
        unsigned short hv[4];
#pragma unroll
        for (int ri = 0; ri < 4; ++ri) hv[ri] = f2h(acc[mf][nf][ri] + bv);
        const size_t idx = ((size_t)(bb * HEADS + h) * HD + d) * NSEQ + n;
        *(ushort4*)(vt_out + idx) = *(ushort4*)hv;
      }
    }
  }
}

// ---------------------------------------------------------------------------
// Flash attention, single-f16 core, fixed-max softmax with exp2.
// P stored PACKED ushort, row stride 72 (aligned b128 reads, no unpack).
// 16 q-rows/wave, grid (16,12,4). LDS 25.6 KB. Output: osp f16.
// ---------------------------------------------------------------------------
__global__ __launch_bounds__(256) void attn_single_k(
    const unsigned short* __restrict__ q_, const unsigned short* __restrict__ kk_,
    const unsigned short* __restrict__ vt_,
    unsigned short* __restrict__ osp)
{
  __shared__ __attribute__((aligned(16))) unsigned char lds[25600];
  unsigned char* const ldsK = lds;
  unsigned char* const ldsV = lds + 8192;

  const int tid  = threadIdx.x;
  const int wave = tid >> 6;
  const int lane = tid & 63;

  int flat = blockIdx.x + 16 * blockIdx.y + 192 * blockIdx.z;
  flat = (flat & 7) * 96 + (flat >> 3);
  const int bxq = flat & 15;
  const int h = (flat >> 4) % 12;
  const int b = flat / 192;
  const int bh = b * HEADS + h;
  const int q0 = bxq * 64 + wave * 16;

  unsigned short* const ldsPs = (unsigned short*)(lds + 16384) + wave * (16 * 72);
  const int arow = lane & 15;
  const int agrp = lane >> 4;

  f16x8 q8[2];
  {
    const unsigned short* qp = q_ + ((size_t)bh * NSEQ + q0 + arow) * HD + agrp * 8;
    q8[0] = *(const f16x8*)qp;
    q8[1] = *(const f16x8*)(qp + 32);
  }

  f32x4 acc[4];
#pragma unroll
  for (int i = 0; i < 4; ++i) acc[i] = f32x4{0.f, 0.f, 0.f, 0.f};
  float l_run[4] = {0.f, 0.f, 0.f, 0.f};

  const int sr = tid >> 3, sc = tid & 7;
  const int swzc = ((sc ^ (sr & 7)) << 3);
  const size_t kbase = (size_t)bh * NSEQ * HD;
  const size_t vbase = (size_t)bh * HD * NSEQ;
  const unsigned short* gK = kk_ + kbase + (size_t)sr * 64 + swzc;
  const unsigned short* gV = vt_ + vbase + (size_t)sr * NSEQ + swzc;
  const int ldsw = (wave * 8) * 128;

  for (int j0 = 0; j0 < NSEQ; j0 += 64) {
    __syncthreads();
    gl16(gK + j0 * 64, ldsK + ldsw);
    gl16(gK + j0 * 64 + 2048, ldsK + ldsw + 4096);
    gl16(gV + j0, ldsV + ldsw);
    gl16(gV + j0 + 32 * NSEQ, ldsV + ldsw + 4096);
    __syncthreads();

    f32x4 s[4];
#pragma unroll
    for (int nt = 0; nt < 4; ++nt) s[nt] = f32x4{0.f, 0.f, 0.f, 0.f};
#pragma unroll
    for (int ks = 0; ks < 2; ++ks) {
#pragma unroll
      for (int nt = 0; nt < 4; ++nt) {
        const int krow = nt * 16 + arow;
        const int chunk = ks * 4 + agrp;
        const int off = krow * 128 + (((chunk ^ (krow & 7)) << 4));
        f16x8 kf = *(const f16x8*)(ldsK + off);
        s[nt] = __builtin_amdgcn_mfma_f32_16x16x32_f16(q8[ks], kf, s[nt], 0, 0, 0);
      }
    }

    // fixed-max softmax: P = exp2(S'), packed ushort stores
#pragma unroll
    for (int nt = 0; nt < 4; ++nt) {
#pragma unroll
      for (int r = 0; r < 4; ++r) {
        float p = __builtin_exp2f(s[nt][r]);
        l_run[r] += p;
        ldsPs[(agrp * 4 + r) * 72 + nt * 16 + arow] = f2h(p);
      }
    }

#pragma unroll
    for (int kk = 0; kk < 2; ++kk) {
      f16x8 p8 = *(const f16x8*)(ldsPs + arow * 72 + kk * 32 + agrp * 8);
#pragma unroll
      for (int nt2 = 0; nt2 < 4; ++nt2) {
        const int vrow = nt2 * 16 + arow;
        const int chunk = kk * 4 + agrp;
        const int off = vrow * 128 + (((chunk ^ (vrow & 7)) << 4));
        f16x8 vf = *(const f16x8*)(ldsV + off);
        acc[nt2] = __builtin_amdgcn_mfma_f32_16x16x32_f16(p8, vf, acc[nt2], 0, 0, 0);
      }
    }
  }

#pragma unroll
  for (int r = 0; r < 4; ++r) {
    float sm = l_run[r];
    sm += __shfl_xor(sm, 1, 64);
    sm += __shfl_xor(sm, 2, 64);
    sm += __shfl_xor(sm, 4, 64);
    sm += __shfl_xor(sm, 8, 64);
    const float inv = 1.f / sm;
    const int n = q0 + agrp * 4 + r;
    const size_t obase = ((size_t)(b * NSEQ + n)) * C_DIM + h * HD + arow;
#pragma unroll
    for (int nt2 = 0; nt2 < 4; ++nt2)
      osp[obase + nt2 * 16] = f2h(acc[nt2][r] * inv);
  }
}

// ---------------------------------------------------------------------------
// Fused attention (steps 4+5): shared QK^T + exp2, two PV passes.
// Packed-ushort P. LDS 33.8 KB.
// ---------------------------------------------------------------------------
__global__ __launch_bounds__(256) void attn_fused_k(
    const unsigned short* __restrict__ q_, const unsigned short* __restrict__ kk_,
    const unsigned short* __restrict__ vA_, const unsigned short* __restrict__ vB_,
    float* __restrict__ out1,
    unsigned short* __restrict__ osp)
{
  __shared__ __attribute__((aligned(16))) unsigned char lds[33792];
  unsigned char* const ldsK = lds;
  unsigned char* const ldsA = lds + 8192;
  unsigned char* const ldsB = lds + 16384;

  const int tid  = threadIdx.x;
  const int wave = tid >> 6;
  const int lane = tid & 63;

  int flat = blockIdx.x + 16 * blockIdx.y + 192 * blockIdx.z;
  flat = (flat & 7) * 96 + (flat >> 3);
  const int bxq = flat & 15;
  const int h = (flat >> 4) % 12;
  const int b = flat / 192;
  const int bh = b * HEADS + h;
  const int q0 = bxq * 64 + wave * 16;

  unsigned short* const ldsPs = (unsigned short*)(lds + 24576) + wave * (16 * 72);
  const int arow = lane & 15;
  const int agrp = lane >> 4;

  f16x8 q8[2];
  {
    const unsigned short* qp = q_ + ((size_t)bh * NSEQ + q0 + arow) * HD + agrp * 8;
    q8[0] = *(const f16x8*)qp;
    q8[1] = *(const f16x8*)(qp + 32);
  }

  f32x4 acc1[4], acc2[4];
#pragma unroll
  for (int i = 0; i < 4; ++i) {
    acc1[i] = f32x4{0.f, 0.f, 0.f, 0.f};
    acc2[i] = f32x4{0.f, 0.f, 0.f, 0.f};
  }
  float l_run[4] = {0.f, 0.f, 0.f, 0.f};

  const int sr = tid >> 3, sc = tid & 7;
  const int swzc = ((sc ^ (sr & 7)) << 3);
  const size_t kbase = (size_t)bh * NSEQ * HD;
  const size_t vbase = (size_t)bh * HD * NSEQ;
  const unsigned short* gK = kk_ + kbase + (size_t)sr * 64 + swzc;
  const unsigned short* gA = vA_ + vbase + (size_t)sr * NSEQ + swzc;
  const unsigned short* gB = vB_ + vbase + (size_t)sr * NSEQ + swzc;
  const int ldsw = (wave * 8) * 128;

  for (int j0 = 0; j0 < NSEQ; j0 += 64) {
    __syncthreads();
    gl16(gK + j0 * 64, ldsK + ldsw);
    gl16(gK + j0 * 64 + 2048, ldsK + ldsw + 4096);
    gl16(gA + j0, ldsA + ldsw);
    gl16(gA + j0 + 32 * NSEQ, ldsA + ldsw + 4096);
    gl16(gB + j0, ldsB + ldsw);
    gl16(gB + j0 + 32 * NSEQ, ldsB + ldsw + 4096);
    __syncthreads();

    f32x4 s[4];
#pragma unroll
    for (int nt = 0; nt < 4; ++nt) s[nt] = f32x4{0.f, 0.f, 0.f, 0.f};
#pragma unroll
    for (int ks = 0; ks < 2; ++ks) {
#pragma unroll
      for (int nt = 0; nt < 4; ++nt) {
        const int krow = nt * 16 + arow;
        const int chunk = ks * 4 + agrp;
        const int off = krow * 128 + (((chunk ^ (krow & 7)) << 4));
        f16x8 kf = *(const f16x8*)(ldsK + off);
        s[nt] = __builtin_amdgcn_mfma_f32_16x16x32_f16(q8[ks], kf, s[nt], 0, 0, 0);
      }
    }

#pragma unroll
    for (int nt = 0; nt < 4; ++nt) {
#pragma unroll
      for (int r = 0; r < 4; ++r) {
        float p = __builtin_exp2f(s[nt][r]);
        l_run[r] += p;
        ldsPs[(agrp * 4 + r) * 72 + nt * 16 + arow] = f2h(p);
      }
    }

#pragma unroll
    for (int kk = 0; kk < 2; ++kk) {
      f16x8 p8 = *(const f16x8*)(ldsPs + arow * 72 + kk * 32 + agrp * 8);
#pragma unroll
      for (int nt2 = 0; nt2 < 4; ++nt2) {
        const int vrow = nt2 * 16 + arow;
        const int chunk = kk * 4 + agrp;
        const int off = vrow * 128 + (((chunk ^ (vrow & 7)) << 4));
        f16x8 va = *(const f16x8*)(ldsA + off);
        f16x8 vb = *(const f16x8*)(ldsB + off);
        acc1[nt2] = __builtin_amdgcn_mfma_f32_16x16x32_f16(p8, va, acc1[nt2], 0, 0, 0);
        acc2[nt2] = __builtin_amdgcn_mfma_f32_16x16x32_f16(p8, vb, acc2[nt2], 0, 0, 0);
      }
    }
  }

#pragma unroll
  for (int r = 0; r < 4; ++r) {
    float sm = l_run[r];
    sm += __shfl_xor(sm, 1, 64);
    sm += __shfl_xor(sm, 2, 64);
    sm += __shfl_xor(sm, 4, 64);
    sm += __shfl_xor(sm, 8, 64);
    const float inv = 1.f / sm;
    const int n = q0 + agrp * 4 + r;
    float* rowp = out1 + (size_t)b * (2048 * C_DIM) + (size_t)n * C_DIM + h * HD + arow;
    const size_t obase = ((size_t)(b * NSEQ + n)) * C_DIM + h * HD + arow;
#pragma unroll
    for (int nt2 = 0; nt2 < 4; ++nt2) {
      rowp[nt2 * 16] = acc1[nt2][r] * inv;
      osp[obase + nt2 * 16] = f2h(acc2[nt2][r] * inv);
    }
  }
}

// ---------------------------------------------------------------------------
extern "C" void kernel_launch(void* const* d_in, const int* in_sizes, int n_in,
                              void* d_out, int out_size, void* d_ws, size_t ws_size,
                              hipStream_t stream)
{
  const float* x           = (const float*)d_in[0];
  const float* w_qkv_diff  = (const float*)d_in[1];
  const float* w_qkv_cond  = (const float*)d_in[2];
  const float* w_proj_diff = (const float*)d_in[3];
  const float* b_proj_diff = (const float*)d_in[4];
  const float* w_proj_cond = (const float*)d_in[5];
  const float* b_proj_cond = (const float*)d_in[6];
  float* out = (float*)d_out;

  const size_t SZ = SZC;
  const size_t WQ = 2304 * 768;
  const size_t WP = 768 * 768;
  unsigned short* sw = (unsigned short*)d_ws;
  // qkv outputs (f16): per half: q, k, vt
  unsigned short* qd  = sw + 0 * SZ;
  unsigned short* kd  = sw + 1 * SZ;
  unsigned short* vtd = sw + 2 * SZ;
  unsigned short* qc  = sw + 3 * SZ;
  unsigned short* kc  = sw + 4 * SZ;
  unsigned short* vtc = sw + 5 * SZ;
  // weights (f16 single)
  unsigned short* wqdT = sw + 6 * SZ;
  unsigned short* wqcT = wqdT + WQ;
  unsigned short* wpdT = wqcT + WQ;
  unsigned short* wpcT = wpdT + WP;
  // osp (f16 single, SZ) after weights
  unsigned short* osp = wpcT + WP;
  // vt2 (f16 single, SZ) aliases qd (dead after step 2)
  unsigned short* vt2 = qd;
  // x f16 scratch: d_out (dead until step 4)
  unsigned short* xs = (unsigned short*)d_out;

  // 0. prep
  split_wT4_k<<<dim3(72, 24, 4), dim3(32, 8), 0, stream>>>(
      w_qkv_diff, w_qkv_cond, w_proj_diff, w_proj_cond,
      wqdT, wqcT, wpdT, wpcT);
  split_x_k<<<dim3(3072), 256, 0, stream>>>(x, xs);

  // 1. qkv both streams -> f16 q(x log2e/8), k, vt(T)
  gemm2_k<0><<<dim3(18, 32, 2), 256, 0, stream>>>(
      xs, wqdT, wqcT, nullptr, sw, nullptr, nullptr);

  // 2. attn_diff -> osp f16
  attn_single_k<<<dim3(16, 12, 4), 256, 0, stream>>>(qd, kd, vtd, osp);

  // 3. (osp @ w_proj_diff + b)^T -> vt2 f16
  gemm2_k<2><<<dim3(6, 32), 256, 0, stream>>>(
      osp, wpdT, nullptr, b_proj_diff, nullptr, nullptr, vt2);

  // 4+5. fused attn_cond: P @ vt2 -> out[:, :N] fp32 ; P @ vtc -> osp f16
  attn_fused_k<<<dim3(16, 12, 4), 256, 0, stream>>>(
      qc, kc, vt2, vtc, out, osp);

  // 6. out[:, N:] = osp @ w_proj_cond + b
  gemm2_k<1><<<dim3(6, 32), 256, 0, stream>>>(
      osp, wpcT, nullptr, b_proj_cond, nullptr, out, nullptr);
}